// Round 8
// baseline (2013.709 us; speedup 1.0000x reference)
//
#include <hip/hip_runtime.h>
#include <cmath>

// ============================================================================
// DPRNN block (intra BiGRU + inter Skip-GRU), all fp32.
// NUMERICS: inter skip-GRU binary gate round(sigmoid(h@Wp)) -> keep fp32.
// Round 8: two fixes to the GRU kernels, everything else untouched:
//  1) amdgpu_waves_per_eu(4,4): launch_bounds' 2nd arg is only a MIN waves/EU;
//     in every prior round the allocator chose 64 VGPRs (8 waves/EU) and
//     demoted U to L2 re-loads (v7: VALUBusy 39%). max=4 caps occupancy
//     ambition -> full 128-reg budget -> U truly register-resident.
//  2) lgkm-only barriers: __syncthreads emits s_waitcnt vmcnt(0) which drains
//     rnn stores + xw prefetch loads every step (~500-900 cyc x4 barriers).
//     No in-kernel cross-thread vmem communication exists, so
//     s_waitcnt lgkmcnt(0) + s_barrier (+ sched_barrier) suffices.
// ============================================================================

typedef float f32x16 __attribute__((ext_vector_type(16)));

__device__ __forceinline__ float sigf(float x) { return 1.0f / (1.0f + expf(-x)); }
__device__ __forceinline__ float rlanef(float v, int l) {
  return __uint_as_float(__builtin_amdgcn_readlane(__float_as_uint(v), (unsigned)l));
}
// LDS-only barrier: orders LDS writes->reads across the block without
// draining vmem (guide §5 8-phase template pattern; rule #18 sched fence).
__device__ __forceinline__ void ldsbar() {
  asm volatile("s_waitcnt lgkmcnt(0)" ::: "memory");
  __builtin_amdgcn_s_barrier();
  __builtin_amdgcn_sched_barrier(0);
}

// 16-k MAC, 2 column groups (intra)
template <int SB>
__device__ __forceinline__ void macP2(const f32x16& u0, const f32x16& u1, float hv,
                                      float& a0, float& a1) {
#pragma unroll
  for (int k = 0; k < 16; ++k) {
    const float hs = rlanef(hv, SB + k);
    a0 = fmaf(u0[k], hs, a0);
    a1 = fmaf(u1[k], hs, a1);
  }
}
// 16-k MAC, 1 column group (intra)
template <int SB>
__device__ __forceinline__ void macP1(const f32x16& u, float hv, float& a) {
#pragma unroll
  for (int k = 0; k < 16; ++k) a = fmaf(u[k], rlanef(hv, SB + k), a);
}

// ---------------------------------------------------------------- fill ones
__global__ __launch_bounds__(256) void k_fill_ones(float* __restrict__ p, int n) {
  int i = blockIdx.x * 256 + threadIdx.x;
  if (i < n) p[i] = 1.0f;
}

// ---------------------------------------------------------------- GEMM (xw precompute)
enum { MA_X_FWD = 0, MA_X_BWD = 1, MA_INTER = 2 };

template <int MODE>
__global__ __launch_bounds__(256) void k_gemm_xw(
    const float* __restrict__ A0, const float* __restrict__ A1,
    const float* __restrict__ Bm, const float* __restrict__ bias,
    float* __restrict__ Cm, long M0, int N, int K, int KT)
{
  __shared__ float As[16][68];
  __shared__ float Bs[16][68];
  const int tid = threadIdx.x;
  const int tx = tid & 15, ty = tid >> 4;
  const long row0g = M0 + (long)blockIdx.x * 64;
  const int col0 = blockIdx.y * 64;
  const int lr = tid >> 2;
  const int lk4 = (tid & 3) * 4;
  const int bk = tid >> 4;
  const int bc4 = (tid & 15) * 4;
  float acc[4][4];
#pragma unroll
  for (int i = 0; i < 4; ++i)
#pragma unroll
    for (int j = 0; j < 4; ++j) acc[i][j] = 0.f;

  for (int kt = 0; kt < KT; ++kt) {
    const int k0 = kt * 16;
    {
      const long rg = row0g + lr;
      float v0, v1, v2, v3;
      if (MODE == MA_X_FWD) {
        const float4 a4 = *reinterpret_cast<const float4*>(&A0[rg * 128 + k0 + lk4]);
        v0 = a4.x; v1 = a4.y; v2 = a4.z; v3 = a4.w;
      } else if (MODE == MA_X_BWD) {
        const long s = rg >> 6; const int t = (int)(rg & 63);
        const float4 a4 =
            *reinterpret_cast<const float4*>(&A0[(s * 64 + (63 - t)) * 128 + k0 + lk4]);
        v0 = a4.x; v1 = a4.y; v2 = a4.z; v3 = a4.w;
      } else {  // MA_INTER: rg = l*1024 + n
        const int n = (int)(rg & 1023);
        const int l = (int)(rg >> 10);
        const long rowc = ((long)(n >> 6) * 200 + l) * 64 + (n & 63);
        const long base = rowc * 128;
        if (kt < 8) {
          const float4 a4 = *reinterpret_cast<const float4*>(&A0[base + k0 + lk4]);
          v0 = a4.x; v1 = a4.y; v2 = a4.z; v3 = a4.w;
        } else {
          v0 = (lk4 == 0) ? A1[rowc] : 0.f;
          v1 = 0.f; v2 = 0.f; v3 = 0.f;
        }
      }
      As[lk4 + 0][lr] = v0;
      As[lk4 + 1][lr] = v1;
      As[lk4 + 2][lr] = v2;
      As[lk4 + 3][lr] = v3;
    }
    {
      const int k = k0 + bk;
      float4 b4 = make_float4(0.f, 0.f, 0.f, 0.f);
      if (k < K) b4 = *reinterpret_cast<const float4*>(&Bm[(long)k * N + col0 + bc4]);
      *reinterpret_cast<float4*>(&Bs[bk][bc4]) = b4;
    }
    __syncthreads();
#pragma unroll
    for (int kk = 0; kk < 16; ++kk) {
      const float4 a4 = *reinterpret_cast<const float4*>(&As[kk][ty * 4]);
      const float4 b4 = *reinterpret_cast<const float4*>(&Bs[kk][tx * 4]);
      const float av[4] = {a4.x, a4.y, a4.z, a4.w};
      const float bv[4] = {b4.x, b4.y, b4.z, b4.w};
#pragma unroll
      for (int i = 0; i < 4; ++i)
#pragma unroll
        for (int j = 0; j < 4; ++j) acc[i][j] = fmaf(av[i], bv[j], acc[i][j]);
    }
    __syncthreads();
  }
  const float4 bi4 = *reinterpret_cast<const float4*>(&bias[col0 + tx * 4]);
  const float bv[4] = {bi4.x, bi4.y, bi4.z, bi4.w};
#pragma unroll
  for (int i = 0; i < 4; ++i) {
    const long rl = (long)blockIdx.x * 64 + ty * 4 + i;
    float4 o;
    o.x = acc[i][0] + bv[0];
    o.y = acc[i][1] + bv[1];
    o.z = acc[i][2] + bv[2];
    o.w = acc[i][3] + bv[3];
    *reinterpret_cast<float4*>(&Cm[rl * (long)N + col0 + tx * 4]) = o;
  }
}

// ---------------------------------------------------------------- intra GRU v5
// = v4 + waves_per_eu(4,4) (U truly resident) + lgkm-only barriers.
__global__ __attribute__((amdgpu_waves_per_eu(4, 4))) __launch_bounds__(256)
void k_gru_intra5(
    const float* __restrict__ xwf, const float* __restrict__ xwb,
    const float* __restrict__ Uf, const float* __restrict__ Ub,
    float* __restrict__ rnn)
{
  const int dir = blockIdx.y;
  const float* __restrict__ xw = dir ? xwb : xwf;
  const float* __restrict__ U  = dir ? Ub : Uf;
  __shared__ float h8[4][64], z8[4][64], rh8[4][64];
  __shared__ float pA[4][4][128];
  __shared__ float pB[4][4][64];
  const int tid = threadIdx.x;
  const int w = tid >> 6, lane = tid & 63;
  const long s0 = (long)blockIdx.x * 4;

  f32x16 uz, ur, uhh;
#pragma unroll
  for (int k = 0; k < 16; ++k) {
    const int row = (w * 16 + k) * 192;
    uz[k]  = U[row + lane];
    ur[k]  = U[row + 64 + lane];
    uhh[k] = U[row + 128 + lane];
  }
  h8[w][lane] = 0.f;
  __syncthreads();

  const long xrow0 = (s0 + w) * 64;
  float xa1 = xw[xrow0 * 192 + lane];
  float xa2 = xw[xrow0 * 192 + 64 + lane];
  float xb  = xw[xrow0 * 192 + 128 + lane];

  for (int t = 0; t < 64; ++t) {
    const int tn = (t < 63) ? t + 1 : t;
    const float xa1n = xw[(xrow0 + tn) * 192 + lane];
    const float xa2n = xw[(xrow0 + tn) * 192 + 64 + lane];
    const float xbn  = xw[(xrow0 + tn) * 192 + 128 + lane];
    {
      const float hv01 = h8[lane >> 5][w * 16 + (lane & 15)];
      const float hv23 = h8[2 + (lane >> 5)][w * 16 + (lane & 15)];
      float az0 = 0.f, ar0 = 0.f, az1 = 0.f, ar1 = 0.f;
      float az2 = 0.f, ar2 = 0.f, az3 = 0.f, ar3 = 0.f;
      macP2<0>(uz, ur, hv01, az0, ar0);
      macP2<32>(uz, ur, hv01, az1, ar1);
      macP2<0>(uz, ur, hv23, az2, ar2);
      macP2<32>(uz, ur, hv23, az3, ar3);
      pA[0][w][lane] = az0; pA[0][w][64 + lane] = ar0;
      pA[1][w][lane] = az1; pA[1][w][64 + lane] = ar1;
      pA[2][w][lane] = az2; pA[2][w][64 + lane] = ar2;
      pA[3][w][lane] = az3; pA[3][w][64 + lane] = ar3;
    }
    ldsbar();
    {
      const float sz = pA[w][0][lane] + pA[w][1][lane] + pA[w][2][lane] +
                       pA[w][3][lane] + xa1;
      const float sr = pA[w][0][64 + lane] + pA[w][1][64 + lane] +
                       pA[w][2][64 + lane] + pA[w][3][64 + lane] + xa2;
      z8[w][lane] = sigf(sz);
      rh8[w][lane] = sigf(sr) * h8[w][lane];
    }
    ldsbar();
    {
      const float rv01 = rh8[lane >> 5][w * 16 + (lane & 15)];
      const float rv23 = rh8[2 + (lane >> 5)][w * 16 + (lane & 15)];
      float a0 = 0.f, a1 = 0.f, a2 = 0.f, a3 = 0.f;
      macP1<0>(uhh, rv01, a0);
      macP1<32>(uhh, rv01, a1);
      macP1<0>(uhh, rv23, a2);
      macP1<32>(uhh, rv23, a3);
      pB[0][w][lane] = a0;
      pB[1][w][lane] = a1;
      pB[2][w][lane] = a2;
      pB[3][w][lane] = a3;
    }
    ldsbar();
    {
      const float pre = pB[w][0][lane] + pB[w][1][lane] + pB[w][2][lane] +
                        pB[w][3][lane] + xb;
      const float hh = tanhf(pre);
      const float z = z8[w][lane];
      const float ho = h8[w][lane];
      const float hn = z * ho + (1.f - z) * hh;
      h8[w][lane] = hn;
      const int tt = dir ? (63 - t) : t;
      rnn[((s0 + w) * 64 + tt) * 128 + dir * 64 + lane] = hn;  // not drained
    }
    ldsbar();
    xa1 = xa1n; xa2 = xa2n; xb = xbn;
  }
}

// ---------------------------------------------------------------- inter skip-GRU v8
// = v7 (512 blocks x 512 thr, 2 seqs, 2 blocks/CU) + waves_per_eu(4,4)
// (128-reg budget honored -> 96 U floats resident) + lgkm-only barriers.
__global__ __attribute__((amdgpu_waves_per_eu(4, 4))) __launch_bounds__(512)
void k_gru_inter8(
    const float* __restrict__ xw, const float* __restrict__ Ui,
    const float* __restrict__ Wp, const float* __restrict__ bp,
    float* __restrict__ rnn, float* __restrict__ gates,
    float* __restrict__ hstate, float* __restrict__ ustate,
    int t0, int nt)
{
  __shared__ float h4[2][128], z4[2][128], rh4[2][128];
  __shared__ float pA[2][8][256];
  __shared__ float pB[2][8][128];
  __shared__ float uu[2], utt[2];
  const int tid = threadIdx.x;
  const int w = tid >> 6, lane = tid & 63;
  const int kb = w << 4;          // k-slice base (16 wide)
  const int n0 = blockIdx.x * 2;

  f32x16 u0, u1, u2, u3;  // zr cols lane, +64, +128, +192
  f32x16 v0, v1;          // hh cols lane, +64
#pragma unroll
  for (int k = 0; k < 16; ++k) {
    const long r = (long)(kb + k) * 384;
    u0[k] = Ui[r + lane];
    u1[k] = Ui[r + 64 + lane];
    u2[k] = Ui[r + 128 + lane];
    u3[k] = Ui[r + 192 + lane];
    v0[k] = Ui[r + 256 + lane];
    v1[k] = Ui[r + 320 + lane];
  }
  if (tid < 256) {
    const int s = tid >> 7, c = tid & 127;
    h4[s][c] = (t0 == 0) ? 0.f : hstate[(long)(n0 + s) * 128 + c];
  }
  if (tid < 2) {
    utt[tid] = (t0 == 0) ? 1.f : ustate[n0 + tid];
    uu[tid]  = (t0 == 0) ? 1.f : ustate[1024 + n0 + tid];
  }
  const float bp0 = bp[0];
  float wpA = 0.f, wpB = 0.f;
  if (w < 2) { wpA = Wp[lane]; wpB = Wp[64 + lane]; }
  __syncthreads();

  const int sC = tid >> 8;   // combineA seq
  const int cC = tid & 255;  // combineA zr col

  for (int dl = 0; dl < nt; ++dl) {
    const float u0g = uu[0], u1g = uu[1];
    const bool act = (u0g + u1g) != 0.f;
    if (act) {
      // issue this-step xw loads early (consumed after b1 / in summer)
      const float xc = xw[((long)dl * 1024 + n0 + sC) * 384 + cC];
      float xbA = 0.f, xbB = 0.f;
      if (w < 2) {
        xbA = xw[((long)dl * 1024 + n0 + w) * 384 + 256 + lane];
        xbB = xw[((long)dl * 1024 + n0 + w) * 384 + 320 + lane];
      }
      {  // ---- phase A ----
        if (u0g != 0.f) {
          const float hv = h4[0][kb + (lane & 15)];
          float a0 = 0.f, a1 = 0.f, a2 = 0.f, a3 = 0.f;
#pragma unroll
          for (int j = 0; j < 16; ++j) {
            const float hs = rlanef(hv, j);
            a0 = fmaf(u0[j], hs, a0);
            a1 = fmaf(u1[j], hs, a1);
            a2 = fmaf(u2[j], hs, a2);
            a3 = fmaf(u3[j], hs, a3);
          }
          pA[0][w][lane] = a0; pA[0][w][64 + lane] = a1;
          pA[0][w][128 + lane] = a2; pA[0][w][192 + lane] = a3;
        }
        if (u1g != 0.f) {
          const float hv = h4[1][kb + (lane & 15)];
          float a0 = 0.f, a1 = 0.f, a2 = 0.f, a3 = 0.f;
#pragma unroll
          for (int j = 0; j < 16; ++j) {
            const float hs = rlanef(hv, j);
            a0 = fmaf(u0[j], hs, a0);
            a1 = fmaf(u1[j], hs, a1);
            a2 = fmaf(u2[j], hs, a2);
            a3 = fmaf(u3[j], hs, a3);
          }
          pA[1][w][lane] = a0; pA[1][w][64 + lane] = a1;
          pA[1][w][128 + lane] = a2; pA[1][w][192 + lane] = a3;
        }
      }
      ldsbar();  // b1
      {  // combineA: thread (sC, cC)
        if (uu[sC] != 0.f) {
          float sum = xc;
#pragma unroll
          for (int q = 0; q < 8; ++q) sum += pA[sC][q][cC];
          if (cC < 128) z4[sC][cC] = sigf(sum);
          else rh4[sC][cC - 128] = sigf(sum) * h4[sC][cC - 128];
        }
      }
      ldsbar();  // b2
      {  // ---- phase B ----
        if (u0g != 0.f) {
          const float rv = rh4[0][kb + (lane & 15)];
          float b0 = 0.f, b1 = 0.f;
#pragma unroll
          for (int j = 0; j < 16; ++j) {
            const float rs = rlanef(rv, j);
            b0 = fmaf(v0[j], rs, b0);
            b1 = fmaf(v1[j], rs, b1);
          }
          pB[0][w][lane] = b0; pB[0][w][64 + lane] = b1;
        }
        if (u1g != 0.f) {
          const float rv = rh4[1][kb + (lane & 15)];
          float b0 = 0.f, b1 = 0.f;
#pragma unroll
          for (int j = 0; j < 16; ++j) {
            const float rs = rlanef(rv, j);
            b0 = fmaf(v0[j], rs, b0);
            b1 = fmaf(v1[j], rs, b1);
          }
          pB[1][w][lane] = b0; pB[1][w][64 + lane] = b1;
        }
      }
      ldsbar();  // b3
      if (w < 2) {  // summer + gate, seq = w (in-wave)
        const float us = uu[w];
        const float hoA = h4[w][lane], hoB = h4[w][64 + lane];
        float hqA, hqB;
        if (us != 0.f) {
          float sA = xbA, sB = xbB;
#pragma unroll
          for (int q = 0; q < 8; ++q) {
            sA += pB[w][q][lane];
            sB += pB[w][q][64 + lane];
          }
          const float hhA = tanhf(sA), hhB = tanhf(sB);
          const float zA = z4[w][lane], zB = z4[w][64 + lane];
          hqA = zA * hoA + (1.f - zA) * hhA;
          hqB = zB * hoB + (1.f - zB) * hhB;
          h4[w][lane] = hqA;
          h4[w][64 + lane] = hqB;
        } else {
          hqA = hoA; hqB = hoB;
        }
        rnn[((long)dl * 1024 + n0 + w) * 128 + lane] = hqA;      // not drained
        rnn[((long)dl * 1024 + n0 + w) * 128 + 64 + lane] = hqB;
        float p = hqA * wpA + hqB * wpB;
        p += __shfl_xor(p, 32);
        p += __shfl_xor(p, 16);
        p += __shfl_xor(p, 8);
        p += __shfl_xor(p, 4);
        p += __shfl_xor(p, 2);
        p += __shfl_xor(p, 1);
        if (lane == 0) {
          const float delta = sigf(p + bp0);
          const float ut = utt[w];
          gates[(long)(n0 + w) * 200 + t0 + dl] = us;
          const float utn = us * delta + (1.f - us) * (ut + fminf(delta, 1.f - ut));
          utt[w] = utn;
          uu[w] = rintf(utn);  // half-to-even, matches jnp.round
        }
      }
    } else {
      // both seqs frozen: h unchanged, still emit rnn snapshot + gates
      if (w < 2) {
        const float hqA = h4[w][lane], hqB = h4[w][64 + lane];
        rnn[((long)dl * 1024 + n0 + w) * 128 + lane] = hqA;
        rnn[((long)dl * 1024 + n0 + w) * 128 + 64 + lane] = hqB;
        float p = hqA * wpA + hqB * wpB;
        p += __shfl_xor(p, 32);
        p += __shfl_xor(p, 16);
        p += __shfl_xor(p, 8);
        p += __shfl_xor(p, 4);
        p += __shfl_xor(p, 2);
        p += __shfl_xor(p, 1);
        if (lane == 0) {
          const float delta = sigf(p + bp0);
          const float ut = utt[w];
          gates[(long)(n0 + w) * 200 + t0 + dl] = 0.f;  // us == 0 here
          const float utn = ut + fminf(delta, 1.f - ut);
          utt[w] = utn;
          uu[w] = rintf(utn);
        }
      }
    }
    ldsbar();  // b4: h4/uu ready for next step
  }
  if (tid < 256) {
    const int s = tid >> 7, c = tid & 127;
    hstate[(long)(n0 + s) * 128 + c] = h4[s][c];
  }
  if (tid < 2) {
    ustate[n0 + tid] = utt[tid];
    ustate[1024 + n0 + tid] = uu[tid];
  }
}

// ---------------------------------------------------------------- FC + LayerNorm + residual
template <int OM>  // 0 = intra (direct rows), 1 = inter (rows rg = l*1024 + n)
__global__ __launch_bounds__(256) void k_fcln(
    const float* __restrict__ A, const float* __restrict__ Wt,
    const float* __restrict__ bias, const float* __restrict__ gamma,
    const float* __restrict__ beta, const float* __restrict__ resid,
    float* __restrict__ dst, long M0)
{
  __shared__ float As[16][36];
  __shared__ float Bs[16][132];
  __shared__ float red0[32][33];
  __shared__ float red1[32][33];
  __shared__ float mu_s[32];
  __shared__ float rs_s[32];
  const int tid = threadIdx.x;
  const int tx = tid & 31, ty = tid >> 5;
  const long r0l = (long)blockIdx.x * 32;
  const int lr = tid >> 3;
  const int lk2 = (tid & 7) * 2;
  const int bkk = tid >> 4;
  const int bc8 = (tid & 15) * 8;
  float acc[4][4];
#pragma unroll
  for (int i = 0; i < 4; ++i)
#pragma unroll
    for (int j = 0; j < 4; ++j) acc[i][j] = 0.f;

  for (int kt = 0; kt < 8; ++kt) {
    const int k0 = kt * 16;
    const float2 a2 = *reinterpret_cast<const float2*>(&A[(r0l + lr) * 128 + k0 + lk2]);
    As[lk2][lr] = a2.x;
    As[lk2 + 1][lr] = a2.y;
    const float4 w0 = *reinterpret_cast<const float4*>(&Wt[(long)(k0 + bkk) * 128 + bc8]);
    const float4 w1 = *reinterpret_cast<const float4*>(&Wt[(long)(k0 + bkk) * 128 + bc8 + 4]);
    *reinterpret_cast<float4*>(&Bs[bkk][bc8]) = w0;
    *reinterpret_cast<float4*>(&Bs[bkk][bc8 + 4]) = w1;
    __syncthreads();
#pragma unroll
    for (int kk = 0; kk < 16; ++kk) {
      const float4 a4 = *reinterpret_cast<const float4*>(&As[kk][ty * 4]);
      const float4 b4 = *reinterpret_cast<const float4*>(&Bs[kk][tx * 4]);
      const float av[4] = {a4.x, a4.y, a4.z, a4.w};
      const float bv[4] = {b4.x, b4.y, b4.z, b4.w};
#pragma unroll
      for (int i = 0; i < 4; ++i)
#pragma unroll
        for (int j = 0; j < 4; ++j) acc[i][j] = fmaf(av[i], bv[j], acc[i][j]);
    }
    __syncthreads();
  }
  {
    const float4 bb4 = *reinterpret_cast<const float4*>(&bias[tx * 4]);
    const float bv[4] = {bb4.x, bb4.y, bb4.z, bb4.w};
#pragma unroll
    for (int i = 0; i < 4; ++i)
#pragma unroll
      for (int j = 0; j < 4; ++j) acc[i][j] += bv[j];
  }
#pragma unroll
  for (int i = 0; i < 4; ++i) {
    const float s = acc[i][0] + acc[i][1] + acc[i][2] + acc[i][3];
    const float q = acc[i][0] * acc[i][0] + acc[i][1] * acc[i][1] +
                    acc[i][2] * acc[i][2] + acc[i][3] * acc[i][3];
    red0[ty * 4 + i][tx] = s;
    red1[ty * 4 + i][tx] = q;
  }
  __syncthreads();
  if (tid < 32) {
    float s = 0.f, q = 0.f;
#pragma unroll
    for (int j = 0; j < 32; ++j) { s += red0[tid][j]; q += red1[tid][j]; }
    const float mu = s * (1.0f / 128.0f);
    const float var = q * (1.0f / 128.0f) - mu * mu;
    mu_s[tid] = mu;
    rs_s[tid] = 1.0f / sqrtf(var + 1e-8f);
  }
  __syncthreads();
  const float4 g4 = *reinterpret_cast<const float4*>(&gamma[tx * 4]);
  const float4 be4 = *reinterpret_cast<const float4*>(&beta[tx * 4]);
#pragma unroll
  for (int i = 0; i < 4; ++i) {
    const int rloc = ty * 4 + i;
    const long rg = M0 + r0l + rloc;
    long off;
    if (OM == 0) {
      off = rg * 128 + tx * 4;
    } else {
      const int n = (int)(rg & 1023);
      const int l = (int)(rg >> 10);
      off = (((long)(n >> 6) * 200 + l) * 64 + (n & 63)) * 128 + tx * 4;
    }
    const float4 r4 = *reinterpret_cast<const float4*>(&resid[off]);
    const float mu = mu_s[rloc], rs = rs_s[rloc];
    float4 o;
    o.x = (acc[i][0] - mu) * rs * g4.x + be4.x + r4.x;
    o.y = (acc[i][1] - mu) * rs * g4.y + be4.y + r4.y;
    o.z = (acc[i][2] - mu) * rs * g4.z + be4.z + r4.z;
    o.w = (acc[i][3] - mu) * rs * g4.w + be4.w + r4.w;
    *reinterpret_cast<float4*>(&dst[off]) = o;
  }
}

// ============================================================================
extern "C" void kernel_launch(void* const* d_in, const int* in_sizes, int n_in,
                              void* d_out, int out_size, void* d_ws, size_t ws_size,
                              hipStream_t stream)
{
  (void)in_sizes; (void)n_in; (void)out_size;
  const float* x    = (const float*)d_in[0];
  const float* scl  = (const float*)d_in[1];
  const float* Wf   = (const float*)d_in[2];
  const float* Uf   = (const float*)d_in[3];
  const float* bf   = (const float*)d_in[4];
  const float* Wb   = (const float*)d_in[5];
  const float* Ub   = (const float*)d_in[6];
  const float* bb   = (const float*)d_in[7];
  const float* Wfc1 = (const float*)d_in[8];
  const float* bfc1 = (const float*)d_in[9];
  const float* gam1 = (const float*)d_in[10];
  const float* bet1 = (const float*)d_in[11];
  const float* Wi   = (const float*)d_in[12];
  const float* Ui   = (const float*)d_in[13];
  const float* bi   = (const float*)d_in[14];
  const float* Wp   = (const float*)d_in[15];
  const float* bp   = (const float*)d_in[16];
  const float* Wfc2 = (const float*)d_in[17];
  const float* bfc2 = (const float*)d_in[18];
  const float* gam2 = (const float*)d_in[19];
  const float* bet2 = (const float*)d_in[20];

  float* outp  = (float*)d_out;
  float* io    = outp;                         // intra_out lives here
  float* onesp = outp + 26214400L;
  float* gates = outp + 26214400L + 12800L;
  float* ws    = (float*)d_ws;
  const long wsf = (long)(ws_size / sizeof(float));

  k_fill_ones<<<50, 256, 0, stream>>>(onesp, 12800);

  // ---------------- intra pass (seq-chunked) ----------------
  long cnI = (wsf / 32768L) & ~7L;
  if (cnI > 3200) cnI = 3200;
  if (cnI < 8) cnI = 8;
  for (long s0 = 0; s0 < 3200; s0 += cnI) {
    const long cn = (3200 - s0 < cnI) ? (3200 - s0) : cnI;
    float* xwf = ws;
    float* xwb = ws + cn * 12288L;
    float* rnn = ws + cn * 24576L;
    const long M = cn * 64;
    dim3 gg((unsigned)(M / 64), 3);
    k_gemm_xw<MA_X_FWD><<<gg, 256, 0, stream>>>(x, nullptr, Wf, bf, xwf, s0 * 64, 192, 128, 8);
    k_gemm_xw<MA_X_BWD><<<gg, 256, 0, stream>>>(x, nullptr, Wb, bb, xwb, s0 * 64, 192, 128, 8);
    dim3 gr((unsigned)(cn / 4), 2);
    k_gru_intra5<<<gr, 256, 0, stream>>>(xwf, xwb, Uf, Ub, rnn);
    k_fcln<0><<<(unsigned)(M / 32), 256, 0, stream>>>(rnn, Wfc1, bfc1, gam1, bet1, x, io, s0 * 64);
  }

  // ---------------- inter pass (t-chunked) ----------------
  const long per_t = 1024L * 384 + 1024L * 128;  // floats per time step
  const long state_f = 1024L * 128 + 3072L;
  long nt_alloc = (wsf - state_f) / per_t;
  if (nt_alloc > 200) nt_alloc = 200;
  if (nt_alloc < 1) nt_alloc = 1;
  float* xwi    = ws;
  float* rnnI   = ws + nt_alloc * 1024L * 384;
  float* hstate = rnnI + nt_alloc * 1024L * 128;
  float* ustate = hstate + 1024L * 128;

  for (long t0 = 0; t0 < 200; t0 += nt_alloc) {
    const int nt = (int)((200 - t0 < nt_alloc) ? (200 - t0) : nt_alloc);
    dim3 gg((unsigned)(16 * nt), 6);
    k_gemm_xw<MA_INTER><<<gg, 256, 0, stream>>>(io, scl, Wi, bi, xwi, t0 * 1024, 384, 129, 9);
    k_gru_inter8<<<512, 512, 0, stream>>>(xwi, Ui, Wp, bp, rnnI, gates, hstate, ustate,
                                          (int)t0, nt);
    k_fcln<1><<<(unsigned)(32 * nt), 256, 0, stream>>>(rnnI, Wfc2, bfc2, gam2, bet2, io, outp,
                                                       t0 * 1024);
  }
}

// Round 9
// 1790.903 us; speedup vs baseline: 1.1244x; 1.1244x over previous
//
#include <hip/hip_runtime.h>
#include <cmath>

// ============================================================================
// DPRNN block (intra BiGRU + inter Skip-GRU), all fp32.
// NUMERICS: inter skip-GRU binary gate round(sigmoid(h@Wp)) -> keep fp32.
// Round 9: inter GRU with PERFECT U PACKING: 256 blocks x 1024 thr (16 waves),
// 4 seqs. Each thread holds exactly 48 U floats (49152/1024): k-slice w*8
// (8 wide), 4 zr cols {l,l+64,l+128,l+192} + 2 hh cols {l,l+64}.
// Readlane amortization: phase A = 8 rl + 32 fma per seq (v3 was 16+64 on
// half the waves; constant-issue plateau across r3-r8 traced to layouts with
// 64-96 U floats/thread -> AGPR spill tax). 4-barrier skeleton (measured
// best), per-seq u-guards, serial gate, xw prefetch, lgkm-only barriers.
// ============================================================================

typedef float f32x16 __attribute__((ext_vector_type(16)));
typedef float f32x8 __attribute__((ext_vector_type(8)));

__device__ __forceinline__ float sigf(float x) { return 1.0f / (1.0f + expf(-x)); }
__device__ __forceinline__ float rlanef(float v, int l) {
  return __uint_as_float(__builtin_amdgcn_readlane(__float_as_uint(v), (unsigned)l));
}
// LDS-only barrier: orders LDS writes->reads without draining vmem.
__device__ __forceinline__ void ldsbar() {
  asm volatile("s_waitcnt lgkmcnt(0)" ::: "memory");
  __builtin_amdgcn_s_barrier();
  __builtin_amdgcn_sched_barrier(0);
}

// 16-k MAC, 2 column groups (intra)
template <int SB>
__device__ __forceinline__ void macP2(const f32x16& u0, const f32x16& u1, float hv,
                                      float& a0, float& a1) {
#pragma unroll
  for (int k = 0; k < 16; ++k) {
    const float hs = rlanef(hv, SB + k);
    a0 = fmaf(u0[k], hs, a0);
    a1 = fmaf(u1[k], hs, a1);
  }
}
// 16-k MAC, 1 column group (intra)
template <int SB>
__device__ __forceinline__ void macP1(const f32x16& u, float hv, float& a) {
#pragma unroll
  for (int k = 0; k < 16; ++k) a = fmaf(u[k], rlanef(hv, SB + k), a);
}

// ---------------------------------------------------------------- fill ones
__global__ __launch_bounds__(256) void k_fill_ones(float* __restrict__ p, int n) {
  int i = blockIdx.x * 256 + threadIdx.x;
  if (i < n) p[i] = 1.0f;
}

// ---------------------------------------------------------------- GEMM (xw precompute)
enum { MA_X_FWD = 0, MA_X_BWD = 1, MA_INTER = 2 };

template <int MODE>
__global__ __launch_bounds__(256) void k_gemm_xw(
    const float* __restrict__ A0, const float* __restrict__ A1,
    const float* __restrict__ Bm, const float* __restrict__ bias,
    float* __restrict__ Cm, long M0, int N, int K, int KT)
{
  __shared__ float As[16][68];
  __shared__ float Bs[16][68];
  const int tid = threadIdx.x;
  const int tx = tid & 15, ty = tid >> 4;
  const long row0g = M0 + (long)blockIdx.x * 64;
  const int col0 = blockIdx.y * 64;
  const int lr = tid >> 2;
  const int lk4 = (tid & 3) * 4;
  const int bk = tid >> 4;
  const int bc4 = (tid & 15) * 4;
  float acc[4][4];
#pragma unroll
  for (int i = 0; i < 4; ++i)
#pragma unroll
    for (int j = 0; j < 4; ++j) acc[i][j] = 0.f;

  for (int kt = 0; kt < KT; ++kt) {
    const int k0 = kt * 16;
    {
      const long rg = row0g + lr;
      float v0, v1, v2, v3;
      if (MODE == MA_X_FWD) {
        const float4 a4 = *reinterpret_cast<const float4*>(&A0[rg * 128 + k0 + lk4]);
        v0 = a4.x; v1 = a4.y; v2 = a4.z; v3 = a4.w;
      } else if (MODE == MA_X_BWD) {
        const long s = rg >> 6; const int t = (int)(rg & 63);
        const float4 a4 =
            *reinterpret_cast<const float4*>(&A0[(s * 64 + (63 - t)) * 128 + k0 + lk4]);
        v0 = a4.x; v1 = a4.y; v2 = a4.z; v3 = a4.w;
      } else {  // MA_INTER: rg = l*1024 + n
        const int n = (int)(rg & 1023);
        const int l = (int)(rg >> 10);
        const long rowc = ((long)(n >> 6) * 200 + l) * 64 + (n & 63);
        const long base = rowc * 128;
        if (kt < 8) {
          const float4 a4 = *reinterpret_cast<const float4*>(&A0[base + k0 + lk4]);
          v0 = a4.x; v1 = a4.y; v2 = a4.z; v3 = a4.w;
        } else {
          v0 = (lk4 == 0) ? A1[rowc] : 0.f;
          v1 = 0.f; v2 = 0.f; v3 = 0.f;
        }
      }
      As[lk4 + 0][lr] = v0;
      As[lk4 + 1][lr] = v1;
      As[lk4 + 2][lr] = v2;
      As[lk4 + 3][lr] = v3;
    }
    {
      const int k = k0 + bk;
      float4 b4 = make_float4(0.f, 0.f, 0.f, 0.f);
      if (k < K) b4 = *reinterpret_cast<const float4*>(&Bm[(long)k * N + col0 + bc4]);
      *reinterpret_cast<float4*>(&Bs[bk][bc4]) = b4;
    }
    __syncthreads();
#pragma unroll
    for (int kk = 0; kk < 16; ++kk) {
      const float4 a4 = *reinterpret_cast<const float4*>(&As[kk][ty * 4]);
      const float4 b4 = *reinterpret_cast<const float4*>(&Bs[kk][tx * 4]);
      const float av[4] = {a4.x, a4.y, a4.z, a4.w};
      const float bv[4] = {b4.x, b4.y, b4.z, b4.w};
#pragma unroll
      for (int i = 0; i < 4; ++i)
#pragma unroll
        for (int j = 0; j < 4; ++j) acc[i][j] = fmaf(av[i], bv[j], acc[i][j]);
    }
    __syncthreads();
  }
  const float4 bi4 = *reinterpret_cast<const float4*>(&bias[col0 + tx * 4]);
  const float bv[4] = {bi4.x, bi4.y, bi4.z, bi4.w};
#pragma unroll
  for (int i = 0; i < 4; ++i) {
    const long rl = (long)blockIdx.x * 64 + ty * 4 + i;
    float4 o;
    o.x = acc[i][0] + bv[0];
    o.y = acc[i][1] + bv[1];
    o.z = acc[i][2] + bv[2];
    o.w = acc[i][3] + bv[3];
    *reinterpret_cast<float4*>(&Cm[rl * (long)N + col0 + tx * 4]) = o;
  }
}

// ---------------------------------------------------------------- intra GRU v5 (r8, kept)
__global__ __attribute__((amdgpu_waves_per_eu(4, 4))) __launch_bounds__(256)
void k_gru_intra5(
    const float* __restrict__ xwf, const float* __restrict__ xwb,
    const float* __restrict__ Uf, const float* __restrict__ Ub,
    float* __restrict__ rnn)
{
  const int dir = blockIdx.y;
  const float* __restrict__ xw = dir ? xwb : xwf;
  const float* __restrict__ U  = dir ? Ub : Uf;
  __shared__ float h8[4][64], z8[4][64], rh8[4][64];
  __shared__ float pA[4][4][128];
  __shared__ float pB[4][4][64];
  const int tid = threadIdx.x;
  const int w = tid >> 6, lane = tid & 63;
  const long s0 = (long)blockIdx.x * 4;

  f32x16 uz, ur, uhh;
#pragma unroll
  for (int k = 0; k < 16; ++k) {
    const int row = (w * 16 + k) * 192;
    uz[k]  = U[row + lane];
    ur[k]  = U[row + 64 + lane];
    uhh[k] = U[row + 128 + lane];
  }
  h8[w][lane] = 0.f;
  __syncthreads();

  const long xrow0 = (s0 + w) * 64;
  float xa1 = xw[xrow0 * 192 + lane];
  float xa2 = xw[xrow0 * 192 + 64 + lane];
  float xb  = xw[xrow0 * 192 + 128 + lane];

  for (int t = 0; t < 64; ++t) {
    const int tn = (t < 63) ? t + 1 : t;
    const float xa1n = xw[(xrow0 + tn) * 192 + lane];
    const float xa2n = xw[(xrow0 + tn) * 192 + 64 + lane];
    const float xbn  = xw[(xrow0 + tn) * 192 + 128 + lane];
    {
      const float hv01 = h8[lane >> 5][w * 16 + (lane & 15)];
      const float hv23 = h8[2 + (lane >> 5)][w * 16 + (lane & 15)];
      float az0 = 0.f, ar0 = 0.f, az1 = 0.f, ar1 = 0.f;
      float az2 = 0.f, ar2 = 0.f, az3 = 0.f, ar3 = 0.f;
      macP2<0>(uz, ur, hv01, az0, ar0);
      macP2<32>(uz, ur, hv01, az1, ar1);
      macP2<0>(uz, ur, hv23, az2, ar2);
      macP2<32>(uz, ur, hv23, az3, ar3);
      pA[0][w][lane] = az0; pA[0][w][64 + lane] = ar0;
      pA[1][w][lane] = az1; pA[1][w][64 + lane] = ar1;
      pA[2][w][lane] = az2; pA[2][w][64 + lane] = ar2;
      pA[3][w][lane] = az3; pA[3][w][64 + lane] = ar3;
    }
    ldsbar();
    {
      const float sz = pA[w][0][lane] + pA[w][1][lane] + pA[w][2][lane] +
                       pA[w][3][lane] + xa1;
      const float sr = pA[w][0][64 + lane] + pA[w][1][64 + lane] +
                       pA[w][2][64 + lane] + pA[w][3][64 + lane] + xa2;
      z8[w][lane] = sigf(sz);
      rh8[w][lane] = sigf(sr) * h8[w][lane];
    }
    ldsbar();
    {
      const float rv01 = rh8[lane >> 5][w * 16 + (lane & 15)];
      const float rv23 = rh8[2 + (lane >> 5)][w * 16 + (lane & 15)];
      float a0 = 0.f, a1 = 0.f, a2 = 0.f, a3 = 0.f;
      macP1<0>(uhh, rv01, a0);
      macP1<32>(uhh, rv01, a1);
      macP1<0>(uhh, rv23, a2);
      macP1<32>(uhh, rv23, a3);
      pB[0][w][lane] = a0;
      pB[1][w][lane] = a1;
      pB[2][w][lane] = a2;
      pB[3][w][lane] = a3;
    }
    ldsbar();
    {
      const float pre = pB[w][0][lane] + pB[w][1][lane] + pB[w][2][lane] +
                        pB[w][3][lane] + xb;
      const float hh = tanhf(pre);
      const float z = z8[w][lane];
      const float ho = h8[w][lane];
      const float hn = z * ho + (1.f - z) * hh;
      h8[w][lane] = hn;
      const int tt = dir ? (63 - t) : t;
      rnn[((s0 + w) * 64 + tt) * 128 + dir * 64 + lane] = hn;
    }
    ldsbar();
    xa1 = xa1n; xa2 = xa2n; xb = xbn;
  }
}

// ---------------------------------------------------------------- inter skip-GRU v9
// 256 blocks x 1024 thr (16 waves), 4 seqs, t-chunked.
// Thread (w, l): k-slice kb=w*8 (8 wide); zr cols {l,l+64,l+128,l+192}
// (32 U regs), hh cols {l,l+64} (16 U regs) -> 48 U floats, perfect packing.
// Phase A per seq: 8 rl + 32 fma. Phase B per seq: 8 rl + 16 fma.
// combineA: tid -> (s=tid>>8, c=tid&255), 16 partials. Summer: waves 0-3.
__global__ __attribute__((amdgpu_waves_per_eu(4, 4))) __launch_bounds__(1024)
void k_gru_inter9(
    const float* __restrict__ xw, const float* __restrict__ Ui,
    const float* __restrict__ Wp, const float* __restrict__ bp,
    float* __restrict__ rnn, float* __restrict__ gates,
    float* __restrict__ hstate, float* __restrict__ ustate,
    int t0, int nt)
{
  __shared__ float h4[4][128], z4[4][128], rh4[4][128];
  __shared__ float pA[4][16][256];
  __shared__ float pB[4][16][128];
  __shared__ float uu[4], utt[4];
  const int tid = threadIdx.x;
  const int w = tid >> 6, lane = tid & 63;
  const int kb = w << 3;          // k-slice base (8 wide)
  const int n0 = blockIdx.x * 4;

  f32x8 u0, u1, u2, u3;  // zr cols lane, +64, +128, +192
  f32x8 v0, v1;          // hh cols lane, +64
#pragma unroll
  for (int k = 0; k < 8; ++k) {
    const long r = (long)(kb + k) * 384;
    u0[k] = Ui[r + lane];
    u1[k] = Ui[r + 64 + lane];
    u2[k] = Ui[r + 128 + lane];
    u3[k] = Ui[r + 192 + lane];
    v0[k] = Ui[r + 256 + lane];
    v1[k] = Ui[r + 320 + lane];
  }
  if (tid < 512) {
    const int s = tid >> 7, c = tid & 127;
    h4[s][c] = (t0 == 0) ? 0.f : hstate[(long)(n0 + s) * 128 + c];
  }
  if (tid < 4) {
    utt[tid] = (t0 == 0) ? 1.f : ustate[n0 + tid];
    uu[tid]  = (t0 == 0) ? 1.f : ustate[1024 + n0 + tid];
  }
  const float bp0 = bp[0];
  float wpA = 0.f, wpB = 0.f;
  if (w < 4) { wpA = Wp[lane]; wpB = Wp[64 + lane]; }
  __syncthreads();

  const int sC = tid >> 8;   // combineA seq (0..3)
  const int cC = tid & 255;  // combineA zr col
  // prefetch xw for dl=0
  float xc = xw[(long)(n0 + sC) * 384 + cC];
  float xbA = 0.f, xbB = 0.f;
  if (w < 4) {
    xbA = xw[(long)(n0 + w) * 384 + 256 + lane];
    xbB = xw[(long)(n0 + w) * 384 + 320 + lane];
  }

  for (int dl = 0; dl < nt; ++dl) {
    const float u0g = uu[0], u1g = uu[1], u2g = uu[2], u3g = uu[3];
    const bool act = (u0g + u1g + u2g + u3g) != 0.f;
    // next-step xw prefetch (unconditional; off critical path)
    const int dn = (dl + 1 < nt) ? dl + 1 : dl;
    const float xcn = xw[((long)dn * 1024 + n0 + sC) * 384 + cC];
    float xbAn = 0.f, xbBn = 0.f;
    if (w < 4) {
      xbAn = xw[((long)dn * 1024 + n0 + w) * 384 + 256 + lane];
      xbBn = xw[((long)dn * 1024 + n0 + w) * 384 + 320 + lane];
    }
    if (act) {
      {  // ---- phase A: all 16 waves, 4 seqs ----
        const float hv01 = h4[lane >> 5][kb + (lane & 7)];      // seqs 0,1
        const float hv23 = h4[2 + (lane >> 5)][kb + (lane & 7)];  // seqs 2,3
        if (u0g != 0.f) {
          float a0 = 0.f, a1 = 0.f, a2 = 0.f, a3 = 0.f;
#pragma unroll
          for (int k = 0; k < 8; ++k) {
            const float hs = rlanef(hv01, k);
            a0 = fmaf(u0[k], hs, a0); a1 = fmaf(u1[k], hs, a1);
            a2 = fmaf(u2[k], hs, a2); a3 = fmaf(u3[k], hs, a3);
          }
          pA[0][w][lane] = a0; pA[0][w][64 + lane] = a1;
          pA[0][w][128 + lane] = a2; pA[0][w][192 + lane] = a3;
        }
        if (u1g != 0.f) {
          float a0 = 0.f, a1 = 0.f, a2 = 0.f, a3 = 0.f;
#pragma unroll
          for (int k = 0; k < 8; ++k) {
            const float hs = rlanef(hv01, 32 + k);
            a0 = fmaf(u0[k], hs, a0); a1 = fmaf(u1[k], hs, a1);
            a2 = fmaf(u2[k], hs, a2); a3 = fmaf(u3[k], hs, a3);
          }
          pA[1][w][lane] = a0; pA[1][w][64 + lane] = a1;
          pA[1][w][128 + lane] = a2; pA[1][w][192 + lane] = a3;
        }
        if (u2g != 0.f) {
          float a0 = 0.f, a1 = 0.f, a2 = 0.f, a3 = 0.f;
#pragma unroll
          for (int k = 0; k < 8; ++k) {
            const float hs = rlanef(hv23, k);
            a0 = fmaf(u0[k], hs, a0); a1 = fmaf(u1[k], hs, a1);
            a2 = fmaf(u2[k], hs, a2); a3 = fmaf(u3[k], hs, a3);
          }
          pA[2][w][lane] = a0; pA[2][w][64 + lane] = a1;
          pA[2][w][128 + lane] = a2; pA[2][w][192 + lane] = a3;
        }
        if (u3g != 0.f) {
          float a0 = 0.f, a1 = 0.f, a2 = 0.f, a3 = 0.f;
#pragma unroll
          for (int k = 0; k < 8; ++k) {
            const float hs = rlanef(hv23, 32 + k);
            a0 = fmaf(u0[k], hs, a0); a1 = fmaf(u1[k], hs, a1);
            a2 = fmaf(u2[k], hs, a2); a3 = fmaf(u3[k], hs, a3);
          }
          pA[3][w][lane] = a0; pA[3][w][64 + lane] = a1;
          pA[3][w][128 + lane] = a2; pA[3][w][192 + lane] = a3;
        }
      }
      ldsbar();  // b1
      {  // combineA: thread (sC, cC)
        if (uu[sC] != 0.f) {
          float sum = xc;
#pragma unroll
          for (int q = 0; q < 16; ++q) sum += pA[sC][q][cC];
          if (cC < 128) z4[sC][cC] = sigf(sum);
          else rh4[sC][cC - 128] = sigf(sum) * h4[sC][cC - 128];
        }
      }
      ldsbar();  // b2
      {  // ---- phase B: all 16 waves, 4 seqs ----
        const float rv01 = rh4[lane >> 5][kb + (lane & 7)];
        const float rv23 = rh4[2 + (lane >> 5)][kb + (lane & 7)];
        if (u0g != 0.f) {
          float b0 = 0.f, b1 = 0.f;
#pragma unroll
          for (int k = 0; k < 8; ++k) {
            const float rs = rlanef(rv01, k);
            b0 = fmaf(v0[k], rs, b0); b1 = fmaf(v1[k], rs, b1);
          }
          pB[0][w][lane] = b0; pB[0][w][64 + lane] = b1;
        }
        if (u1g != 0.f) {
          float b0 = 0.f, b1 = 0.f;
#pragma unroll
          for (int k = 0; k < 8; ++k) {
            const float rs = rlanef(rv01, 32 + k);
            b0 = fmaf(v0[k], rs, b0); b1 = fmaf(v1[k], rs, b1);
          }
          pB[1][w][lane] = b0; pB[1][w][64 + lane] = b1;
        }
        if (u2g != 0.f) {
          float b0 = 0.f, b1 = 0.f;
#pragma unroll
          for (int k = 0; k < 8; ++k) {
            const float rs = rlanef(rv23, k);
            b0 = fmaf(v0[k], rs, b0); b1 = fmaf(v1[k], rs, b1);
          }
          pB[2][w][lane] = b0; pB[2][w][64 + lane] = b1;
        }
        if (u3g != 0.f) {
          float b0 = 0.f, b1 = 0.f;
#pragma unroll
          for (int k = 0; k < 8; ++k) {
            const float rs = rlanef(rv23, 32 + k);
            b0 = fmaf(v0[k], rs, b0); b1 = fmaf(v1[k], rs, b1);
          }
          pB[3][w][lane] = b0; pB[3][w][64 + lane] = b1;
        }
      }
      ldsbar();  // b3
      if (w < 4) {  // summer + gate, seq = w
        const float us = uu[w];
        const float hoA = h4[w][lane], hoB = h4[w][64 + lane];
        float hqA, hqB;
        if (us != 0.f) {
          float sA = xbA, sB = xbB;
#pragma unroll
          for (int q = 0; q < 16; ++q) {
            sA += pB[w][q][lane];
            sB += pB[w][q][64 + lane];
          }
          const float hhA = tanhf(sA), hhB = tanhf(sB);
          const float zA = z4[w][lane], zB = z4[w][64 + lane];
          hqA = zA * hoA + (1.f - zA) * hhA;
          hqB = zB * hoB + (1.f - zB) * hhB;
          h4[w][lane] = hqA;
          h4[w][64 + lane] = hqB;
        } else {
          hqA = hoA; hqB = hoB;
        }
        rnn[((long)dl * 1024 + n0 + w) * 128 + lane] = hqA;
        rnn[((long)dl * 1024 + n0 + w) * 128 + 64 + lane] = hqB;
        float p = hqA * wpA + hqB * wpB;
        p += __shfl_xor(p, 32);
        p += __shfl_xor(p, 16);
        p += __shfl_xor(p, 8);
        p += __shfl_xor(p, 4);
        p += __shfl_xor(p, 2);
        p += __shfl_xor(p, 1);
        if (lane == 0) {
          const float delta = sigf(p + bp0);
          const float ut = utt[w];
          gates[(long)(n0 + w) * 200 + t0 + dl] = us;
          const float utn = us * delta + (1.f - us) * (ut + fminf(delta, 1.f - ut));
          utt[w] = utn;
          uu[w] = rintf(utn);  // half-to-even, matches jnp.round
        }
      }
    } else {
      // all 4 seqs frozen: h unchanged, still emit rnn snapshot + gates
      if (w < 4) {
        const float hqA = h4[w][lane], hqB = h4[w][64 + lane];
        rnn[((long)dl * 1024 + n0 + w) * 128 + lane] = hqA;
        rnn[((long)dl * 1024 + n0 + w) * 128 + 64 + lane] = hqB;
        float p = hqA * wpA + hqB * wpB;
        p += __shfl_xor(p, 32);
        p += __shfl_xor(p, 16);
        p += __shfl_xor(p, 8);
        p += __shfl_xor(p, 4);
        p += __shfl_xor(p, 2);
        p += __shfl_xor(p, 1);
        if (lane == 0) {
          const float delta = sigf(p + bp0);
          const float ut = utt[w];
          gates[(long)(n0 + w) * 200 + t0 + dl] = 0.f;  // us == 0 here
          const float utn = ut + fminf(delta, 1.f - ut);
          utt[w] = utn;
          uu[w] = rintf(utn);
        }
      }
    }
    ldsbar();  // b4: h4/uu ready for next step
    xc = xcn; xbA = xbAn; xbB = xbBn;
  }
  if (tid < 512) {
    const int s = tid >> 7, c = tid & 127;
    hstate[(long)(n0 + s) * 128 + c] = h4[s][c];
  }
  if (tid < 4) {
    ustate[n0 + tid] = utt[tid];
    ustate[1024 + n0 + tid] = uu[tid];
  }
}

// ---------------------------------------------------------------- FC + LayerNorm + residual
template <int OM>  // 0 = intra (direct rows), 1 = inter (rows rg = l*1024 + n)
__global__ __launch_bounds__(256) void k_fcln(
    const float* __restrict__ A, const float* __restrict__ Wt,
    const float* __restrict__ bias, const float* __restrict__ gamma,
    const float* __restrict__ beta, const float* __restrict__ resid,
    float* __restrict__ dst, long M0)
{
  __shared__ float As[16][36];
  __shared__ float Bs[16][132];
  __shared__ float red0[32][33];
  __shared__ float red1[32][33];
  __shared__ float mu_s[32];
  __shared__ float rs_s[32];
  const int tid = threadIdx.x;
  const int tx = tid & 31, ty = tid >> 5;
  const long r0l = (long)blockIdx.x * 32;
  const int lr = tid >> 3;
  const int lk2 = (tid & 7) * 2;
  const int bkk = tid >> 4;
  const int bc8 = (tid & 15) * 8;
  float acc[4][4];
#pragma unroll
  for (int i = 0; i < 4; ++i)
#pragma unroll
    for (int j = 0; j < 4; ++j) acc[i][j] = 0.f;

  for (int kt = 0; kt < 8; ++kt) {
    const int k0 = kt * 16;
    const float2 a2 = *reinterpret_cast<const float2*>(&A[(r0l + lr) * 128 + k0 + lk2]);
    As[lk2][lr] = a2.x;
    As[lk2 + 1][lr] = a2.y;
    const float4 w0 = *reinterpret_cast<const float4*>(&Wt[(long)(k0 + bkk) * 128 + bc8]);
    const float4 w1 = *reinterpret_cast<const float4*>(&Wt[(long)(k0 + bkk) * 128 + bc8 + 4]);
    *reinterpret_cast<float4*>(&Bs[bkk][bc8]) = w0;
    *reinterpret_cast<float4*>(&Bs[bkk][bc8 + 4]) = w1;
    __syncthreads();
#pragma unroll
    for (int kk = 0; kk < 16; ++kk) {
      const float4 a4 = *reinterpret_cast<const float4*>(&As[kk][ty * 4]);
      const float4 b4 = *reinterpret_cast<const float4*>(&Bs[kk][tx * 4]);
      const float av[4] = {a4.x, a4.y, a4.z, a4.w};
      const float bv[4] = {b4.x, b4.y, b4.z, b4.w};
#pragma unroll
      for (int i = 0; i < 4; ++i)
#pragma unroll
        for (int j = 0; j < 4; ++j) acc[i][j] = fmaf(av[i], bv[j], acc[i][j]);
    }
    __syncthreads();
  }
  {
    const float4 bb4 = *reinterpret_cast<const float4*>(&bias[tx * 4]);
    const float bv[4] = {bb4.x, bb4.y, bb4.z, bb4.w};
#pragma unroll
    for (int i = 0; i < 4; ++i)
#pragma unroll
      for (int j = 0; j < 4; ++j) acc[i][j] += bv[j];
  }
#pragma unroll
  for (int i = 0; i < 4; ++i) {
    const float s = acc[i][0] + acc[i][1] + acc[i][2] + acc[i][3];
    const float q = acc[i][0] * acc[i][0] + acc[i][1] * acc[i][1] +
                    acc[i][2] * acc[i][2] + acc[i][3] * acc[i][3];
    red0[ty * 4 + i][tx] = s;
    red1[ty * 4 + i][tx] = q;
  }
  __syncthreads();
  if (tid < 32) {
    float s = 0.f, q = 0.f;
#pragma unroll
    for (int j = 0; j < 32; ++j) { s += red0[tid][j]; q += red1[tid][j]; }
    const float mu = s * (1.0f / 128.0f);
    const float var = q * (1.0f / 128.0f) - mu * mu;
    mu_s[tid] = mu;
    rs_s[tid] = 1.0f / sqrtf(var + 1e-8f);
  }
  __syncthreads();
  const float4 g4 = *reinterpret_cast<const float4*>(&gamma[tx * 4]);
  const float4 be4 = *reinterpret_cast<const float4*>(&beta[tx * 4]);
#pragma unroll
  for (int i = 0; i < 4; ++i) {
    const int rloc = ty * 4 + i;
    const long rg = M0 + r0l + rloc;
    long off;
    if (OM == 0) {
      off = rg * 128 + tx * 4;
    } else {
      const int n = (int)(rg & 1023);
      const int l = (int)(rg >> 10);
      off = (((long)(n >> 6) * 200 + l) * 64 + (n & 63)) * 128 + tx * 4;
    }
    const float4 r4 = *reinterpret_cast<const float4*>(&resid[off]);
    const float mu = mu_s[rloc], rs = rs_s[rloc];
    float4 o;
    o.x = (acc[i][0] - mu) * rs * g4.x + be4.x + r4.x;
    o.y = (acc[i][1] - mu) * rs * g4.y + be4.y + r4.y;
    o.z = (acc[i][2] - mu) * rs * g4.z + be4.z + r4.z;
    o.w = (acc[i][3] - mu) * rs * g4.w + be4.w + r4.w;
    *reinterpret_cast<float4*>(&dst[off]) = o;
  }
}

// ============================================================================
extern "C" void kernel_launch(void* const* d_in, const int* in_sizes, int n_in,
                              void* d_out, int out_size, void* d_ws, size_t ws_size,
                              hipStream_t stream)
{
  (void)in_sizes; (void)n_in; (void)out_size;
  const float* x    = (const float*)d_in[0];
  const float* scl  = (const float*)d_in[1];
  const float* Wf   = (const float*)d_in[2];
  const float* Uf   = (const float*)d_in[3];
  const float* bf   = (const float*)d_in[4];
  const float* Wb   = (const float*)d_in[5];
  const float* Ub   = (const float*)d_in[6];
  const float* bb   = (const float*)d_in[7];
  const float* Wfc1 = (const float*)d_in[8];
  const float* bfc1 = (const float*)d_in[9];
  const float* gam1 = (const float*)d_in[10];
  const float* bet1 = (const float*)d_in[11];
  const float* Wi   = (const float*)d_in[12];
  const float* Ui   = (const float*)d_in[13];
  const float* bi   = (const float*)d_in[14];
  const float* Wp   = (const float*)d_in[15];
  const float* bp   = (const float*)d_in[16];
  const float* Wfc2 = (const float*)d_in[17];
  const float* bfc2 = (const float*)d_in[18];
  const float* gam2 = (const float*)d_in[19];
  const float* bet2 = (const float*)d_in[20];

  float* outp  = (float*)d_out;
  float* io    = outp;                         // intra_out lives here
  float* onesp = outp + 26214400L;
  float* gates = outp + 26214400L + 12800L;
  float* ws    = (float*)d_ws;
  const long wsf = (long)(ws_size / sizeof(float));

  k_fill_ones<<<50, 256, 0, stream>>>(onesp, 12800);

  // ---------------- intra pass (seq-chunked) ----------------
  long cnI = (wsf / 32768L) & ~7L;
  if (cnI > 3200) cnI = 3200;
  if (cnI < 8) cnI = 8;
  for (long s0 = 0; s0 < 3200; s0 += cnI) {
    const long cn = (3200 - s0 < cnI) ? (3200 - s0) : cnI;
    float* xwf = ws;
    float* xwb = ws + cn * 12288L;
    float* rnn = ws + cn * 24576L;
    const long M = cn * 64;
    dim3 gg((unsigned)(M / 64), 3);
    k_gemm_xw<MA_X_FWD><<<gg, 256, 0, stream>>>(x, nullptr, Wf, bf, xwf, s0 * 64, 192, 128, 8);
    k_gemm_xw<MA_X_BWD><<<gg, 256, 0, stream>>>(x, nullptr, Wb, bb, xwb, s0 * 64, 192, 128, 8);
    dim3 gr((unsigned)(cn / 4), 2);
    k_gru_intra5<<<gr, 256, 0, stream>>>(xwf, xwb, Uf, Ub, rnn);
    k_fcln<0><<<(unsigned)(M / 32), 256, 0, stream>>>(rnn, Wfc1, bfc1, gam1, bet1, x, io, s0 * 64);
  }

  // ---------------- inter pass (t-chunked) ----------------
  const long per_t = 1024L * 384 + 1024L * 128;  // floats per time step
  const long state_f = 1024L * 128 + 3072L;
  long nt_alloc = (wsf - state_f) / per_t;
  if (nt_alloc > 200) nt_alloc = 200;
  if (nt_alloc < 1) nt_alloc = 1;
  float* xwi    = ws;
  float* rnnI   = ws + nt_alloc * 1024L * 384;
  float* hstate = rnnI + nt_alloc * 1024L * 128;
  float* ustate = hstate + 1024L * 128;

  for (long t0 = 0; t0 < 200; t0 += nt_alloc) {
    const int nt = (int)((200 - t0 < nt_alloc) ? (200 - t0) : nt_alloc);
    dim3 gg((unsigned)(16 * nt), 6);
    k_gemm_xw<MA_INTER><<<gg, 256, 0, stream>>>(io, scl, Wi, bi, xwi, t0 * 1024, 384, 129, 9);
    k_gru_inter9<<<256, 1024, 0, stream>>>(xwi, Ui, Wp, bp, rnnI, gates, hstate, ustate,
                                           (int)t0, nt);
    k_fcln<1><<<(unsigned)(32 * nt), 256, 0, stream>>>(rnnI, Wfc2, bfc2, gam2, bet2, io, outp,
                                                       t0 * 1024);
  }
}